// Round 1
// baseline (543.476 us; speedup 1.0000x reference)
//
#include <hip/hip_runtime.h>

#define DD 512      // feature dim
#define NTOP 10     // topic_e
#define NTK 6       // num_topics
#define NPAIR 60    // NTOP*NTK
#define TS 64       // GEMM tile
#define KC 32       // K-chunk

// ---------------------------------------------------------------------------
// Kernel 1: per-row argmax over topics (W_max) + inverse norms.
// One 64-lane wave per row; x row staged in LDS; lanes 0..59 each compute one
// (t,i) dot product with coalesced H reads (H[d*60 + lane]).
// ---------------------------------------------------------------------------
__global__ __launch_bounds__(64) void kern_wmax(
    const float* __restrict__ x, const float* __restrict__ H,
    int* __restrict__ wmax, float* __restrict__ inv_norm)
{
  __shared__ float xs[DD];
  __shared__ float w[NPAIR];
  const int n = blockIdx.x;
  const int lane = threadIdx.x;
  const float* xr = x + (size_t)n * DD;
  float ss = 0.f;
#pragma unroll
  for (int j = 0; j < DD / 64; ++j) {
    float v = xr[lane + 64 * j];
    xs[lane + 64 * j] = v;
    ss += v * v;
  }
#pragma unroll
  for (int off = 32; off; off >>= 1) ss += __shfl_xor(ss, off);
  if (lane == 0) inv_norm[n] = 1.0f / fmaxf(sqrtf(ss), 1e-8f);
  __syncthreads();
  if (lane < NPAIR) {
    float acc = 0.f;
#pragma unroll 16
    for (int d = 0; d < DD; ++d) acc = fmaf(xs[d], H[d * NPAIR + lane], acc);
    w[lane] = acc;
  }
  __syncthreads();
  if (lane < NTK) {
    float best = w[lane];
    int bi = 0;
#pragma unroll
    for (int t = 1; t < NTOP; ++t) {
      float v = w[t * NTK + lane];
      if (v > best) { best = v; bi = t; }  // strict > keeps first index (jnp.argmax tie rule)
    }
    wmax[n * NTK + lane] = bi;
  }
}

// ---------------------------------------------------------------------------
// Kernel 2: C[a,b] = F(a,b) * (x_a . x_b) * inv|a| * inv|b|, materialized to ws.
// 64x64 tile per 256-thread block, 4x4 register accumulator per thread.
// Also accumulates col_sum[b] = sum_a C[a,b] (LDS partial -> 1 global atomic).
// ---------------------------------------------------------------------------
__global__ __launch_bounds__(256) void kern_ctile(
    const float* __restrict__ x, const int* __restrict__ wmax,
    const float* __restrict__ inv_norm, float* __restrict__ Cmat,
    float* __restrict__ col_sum, int N)
{
  __shared__ float As[KC][TS];   // K-major
  __shared__ float Bs[KC][TS];
  __shared__ int   wAf[TS * NTK];
  __shared__ int   wBf[TS * NTK];
  __shared__ float invA[TS], invB[TS];
  __shared__ float csum[TS];

  const int a0 = blockIdx.y * TS;
  const int b0 = blockIdx.x * TS;
  const int tid = threadIdx.x;
  const int tx = tid & 15, ty = tid >> 4;

  for (int i = tid; i < TS * NTK; i += 256) {
    wAf[i] = wmax[a0 * NTK + i];
    wBf[i] = wmax[b0 * NTK + i];
  }
  if (tid < TS) { invA[tid] = inv_norm[a0 + tid]; csum[tid] = 0.f; }
  else if (tid < 2 * TS) invB[tid - TS] = inv_norm[b0 + tid - TS];

  float acc[4][4] = {};
  for (int kc = 0; kc < DD; kc += KC) {
#pragma unroll
    for (int l = 0; l < 2; ++l) {
      int idx = tid + l * 256;          // 0..511 covers 64 rows x 8 float4
      int row = idx >> 3, c4 = idx & 7;
      float4 va = *(const float4*)&x[(size_t)(a0 + row) * DD + kc + c4 * 4];
      float4 vb = *(const float4*)&x[(size_t)(b0 + row) * DD + kc + c4 * 4];
      As[c4 * 4 + 0][row] = va.x; As[c4 * 4 + 1][row] = va.y;
      As[c4 * 4 + 2][row] = va.z; As[c4 * 4 + 3][row] = va.w;
      Bs[c4 * 4 + 0][row] = vb.x; Bs[c4 * 4 + 1][row] = vb.y;
      Bs[c4 * 4 + 2][row] = vb.z; Bs[c4 * 4 + 3][row] = vb.w;
    }
    __syncthreads();
#pragma unroll
    for (int k = 0; k < KC; ++k) {
      float4 a = *(const float4*)&As[k][ty * 4];
      float4 b = *(const float4*)&Bs[k][tx * 4];
      float av[4] = {a.x, a.y, a.z, a.w};
      float bv[4] = {b.x, b.y, b.z, b.w};
#pragma unroll
      for (int i = 0; i < 4; ++i)
#pragma unroll
        for (int j = 0; j < 4; ++j)
          acc[i][j] = fmaf(av[i], bv[j], acc[i][j]);
    }
    __syncthreads();
  }

  // epilogue: scale by norms, multiply by topic-match fraction, write C
  int wa[4][NTK], wb[4][NTK];
  float ia[4], ib[4];
#pragma unroll
  for (int i = 0; i < 4; ++i) {
#pragma unroll
    for (int k = 0; k < NTK; ++k) {
      wa[i][k] = wAf[(ty * 4 + i) * NTK + k];
      wb[i][k] = wBf[(tx * 4 + i) * NTK + k];
    }
    ia[i] = invA[ty * 4 + i];
    ib[i] = invB[tx * 4 + i];
  }
  float colacc[4] = {};
#pragma unroll
  for (int i = 0; i < 4; ++i) {
    float tmp[4];
#pragma unroll
    for (int j = 0; j < 4; ++j) {
      int cnt = 0;
#pragma unroll
      for (int k = 0; k < NTK; ++k) cnt += (wa[i][k] == wb[j][k]);
      float cval = acc[i][j] * ia[i] * ib[j] * ((float)cnt * (1.0f / 6.0f));
      tmp[j] = cval;
      colacc[j] += cval;
    }
    float4 ov = {tmp[0], tmp[1], tmp[2], tmp[3]};
    *(float4*)&Cmat[(size_t)(a0 + ty * 4 + i) * N + b0 + tx * 4] = ov;
  }
#pragma unroll
  for (int j = 0; j < 4; ++j) atomicAdd(&csum[tx * 4 + j], colacc[j]);
  __syncthreads();
  if (tid < TS) atomicAdd(&col_sum[b0 + tid], csum[tid]);
}

// ---------------------------------------------------------------------------
// Kernel 3: out_second[b,d] = (1/N) * sum_a C[a,b] * x[a,d]  (GEMM, K=N)
// ---------------------------------------------------------------------------
__global__ __launch_bounds__(256) void kern_out2(
    const float* __restrict__ Cmat, const float* __restrict__ x,
    float* __restrict__ out, int N)
{
  __shared__ float Cs[KC][TS];
  __shared__ float Xs[KC][TS];
  const int b0 = blockIdx.x * TS;
  const int d0 = blockIdx.y * TS;
  const int tid = threadIdx.x;
  const int tx = tid & 15, ty = tid >> 4;
  float acc[4][4] = {};
  for (int a = 0; a < N; a += KC) {
#pragma unroll
    for (int l = 0; l < 2; ++l) {
      int idx = tid + l * 256;          // 0..511 covers 32 rows x 16 float4
      int row = idx >> 4, c4 = idx & 15;
      float4 vc = *(const float4*)&Cmat[(size_t)(a + row) * N + b0 + c4 * 4];
      float4 vx = *(const float4*)&x[(size_t)(a + row) * DD + d0 + c4 * 4];
      *(float4*)&Cs[row][c4 * 4] = vc;
      *(float4*)&Xs[row][c4 * 4] = vx;
    }
    __syncthreads();
#pragma unroll
    for (int k = 0; k < KC; ++k) {
      float4 b = *(const float4*)&Cs[k][ty * 4];
      float4 xf = *(const float4*)&Xs[k][tx * 4];
      float bv[4] = {b.x, b.y, b.z, b.w};
      float xv[4] = {xf.x, xf.y, xf.z, xf.w};
#pragma unroll
      for (int i = 0; i < 4; ++i)
#pragma unroll
        for (int j = 0; j < 4; ++j)
          acc[i][j] = fmaf(bv[i], xv[j], acc[i][j]);
    }
    __syncthreads();
  }
  const float invN = 1.0f / (float)N;
#pragma unroll
  for (int i = 0; i < 4; ++i) {
    float4 o = {acc[i][0] * invN, acc[i][1] * invN, acc[i][2] * invN, acc[i][3] * invN};
    *(float4*)&out[(size_t)(b0 + ty * 4 + i) * (2 * DD) + DD + d0 + tx * 4] = o;
  }
}

// ---------------------------------------------------------------------------
// Kernel 4: out_first[n,d] = x[n,d] * col_sum[n] / N
// ---------------------------------------------------------------------------
__global__ __launch_bounds__(256) void kern_out1(
    const float* __restrict__ x, const float* __restrict__ col_sum,
    float* __restrict__ out, int N)
{
  int idx = blockIdx.x * 256 + threadIdx.x;
  int total = N * (DD / 4);
  if (idx >= total) return;
  int n = idx / (DD / 4);
  int d4 = idx - n * (DD / 4);
  float s = col_sum[n] * (1.0f / (float)N);
  float4 v = ((const float4*)(x + (size_t)n * DD))[d4];
  v.x *= s; v.y *= s; v.z *= s; v.w *= s;
  *(float4*)&out[(size_t)n * (2 * DD) + d4 * 4] = v;
}

extern "C" void kernel_launch(void* const* d_in, const int* in_sizes, int n_in,
                              void* d_out, int out_size, void* d_ws, size_t ws_size,
                              hipStream_t stream) {
  const float* x = (const float*)d_in[0];
  const float* H = (const float*)d_in[1];
  float* out = (float*)d_out;
  const int N = in_sizes[0] / DD;  // 4096

  char* ws = (char*)d_ws;
  float* Cmat     = (float*)ws;                                   // N*N floats (64 MB)
  float* col_sum  = (float*)(ws + (size_t)N * N * sizeof(float)); // N floats
  float* inv_norm = col_sum + N;                                  // N floats
  int*   wmax     = (int*)(inv_norm + N);                         // N*6 ints

  hipMemsetAsync(col_sum, 0, N * sizeof(float), stream);
  kern_wmax<<<N, 64, 0, stream>>>(x, H, wmax, inv_norm);
  kern_ctile<<<dim3(N / TS, N / TS), 256, 0, stream>>>(x, wmax, inv_norm, Cmat, col_sum, N);
  kern_out2<<<dim3(N / TS, DD / TS), 256, 0, stream>>>(Cmat, x, out, N);
  kern_out1<<<(N * (DD / 4) + 255) / 256, 256, 0, stream>>>(x, col_sum, out, N);
}

// Round 2
// 110.737 us; speedup vs baseline: 4.9078x; 4.9078x over previous
//
#include <hip/hip_runtime.h>
#include <hip/hip_bf16.h>

#define DD 512      // feature dim
#define NTOP 10     // topic_e
#define NTK 6       // num_topics
#define NPAIR 60    // NTOP*NTK

typedef float f32x4 __attribute__((ext_vector_type(4)));
typedef short bf16x8 __attribute__((ext_vector_type(8)));
typedef unsigned short us8 __attribute__((ext_vector_type(8)));

__device__ __forceinline__ void gload16(const void* g, void* l) {
  __builtin_amdgcn_global_load_lds(
      (const __attribute__((address_space(1))) unsigned int*)g,
      (__attribute__((address_space(3))) unsigned int*)l, 16, 0, 0);
}

// ---------------------------------------------------------------------------
// Kernel 1: per-row argmax over topics (packed nibble code) + inverse norm.
// ---------------------------------------------------------------------------
__global__ __launch_bounds__(64) void kern_wmax(
    const float* __restrict__ x, const float* __restrict__ H,
    int* __restrict__ codes, float* __restrict__ inv_norm)
{
  __shared__ float xs[DD];
  __shared__ float w[NPAIR];
  __shared__ int csh[NTK];
  const int n = blockIdx.x;
  const int lane = threadIdx.x;
  const float* xr = x + (size_t)n * DD;
  float ss = 0.f;
#pragma unroll
  for (int j = 0; j < DD / 64; ++j) {
    float v = xr[lane + 64 * j];
    xs[lane + 64 * j] = v;
    ss += v * v;
  }
#pragma unroll
  for (int off = 32; off; off >>= 1) ss += __shfl_xor(ss, off);
  if (lane == 0) inv_norm[n] = 1.0f / fmaxf(sqrtf(ss), 1e-8f);
  __syncthreads();
  if (lane < NPAIR) {
    float acc = 0.f;
#pragma unroll 16
    for (int d = 0; d < DD; ++d) acc = fmaf(xs[d], H[d * NPAIR + lane], acc);
    w[lane] = acc;
  }
  __syncthreads();
  if (lane < NTK) {
    float best = w[lane];
    int bi = 0;
#pragma unroll
    for (int t = 1; t < NTOP; ++t) {
      float v = w[t * NTK + lane];
      if (v > best) { best = v; bi = t; }  // strict > == jnp.argmax first-index tie rule
    }
    csh[lane] = bi << (4 * lane);
  }
  __syncthreads();
  if (lane == 0)
    codes[n] = csh[0] | csh[1] | csh[2] | csh[3] | csh[4] | csh[5];
}

// ---------------------------------------------------------------------------
// Kernel 2: xn = bf16(x * inv_norm) row-major; xT = bf16(x)^T  (D x N)
// 64x64 tile per block; LDS transpose with +1 pad.
// ---------------------------------------------------------------------------
__global__ __launch_bounds__(256) void kern_prep(
    const float* __restrict__ x, const float* __restrict__ inv_norm,
    __hip_bfloat16* __restrict__ xn, __hip_bfloat16* __restrict__ xT, int N)
{
  __shared__ float tile[64][65];
  const int n0 = blockIdx.x * 64, d0 = blockIdx.y * 64;
  const int tid = threadIdx.x;
  const int r = tid >> 2, cseg = (tid & 3) * 16;
  const float* src = x + (size_t)(n0 + r) * DD + d0 + cseg;
  const float invn = inv_norm[n0 + r];
  unsigned short hb[16];
#pragma unroll
  for (int q = 0; q < 4; ++q) {
    float4 v = *(const float4*)(src + q * 4);
    tile[r][cseg + q * 4 + 0] = v.x; tile[r][cseg + q * 4 + 1] = v.y;
    tile[r][cseg + q * 4 + 2] = v.z; tile[r][cseg + q * 4 + 3] = v.w;
    hb[q * 4 + 0] = __builtin_bit_cast(unsigned short, __float2bfloat16(v.x * invn));
    hb[q * 4 + 1] = __builtin_bit_cast(unsigned short, __float2bfloat16(v.y * invn));
    hb[q * 4 + 2] = __builtin_bit_cast(unsigned short, __float2bfloat16(v.z * invn));
    hb[q * 4 + 3] = __builtin_bit_cast(unsigned short, __float2bfloat16(v.w * invn));
  }
  us8 v0, v1;
#pragma unroll
  for (int i = 0; i < 8; ++i) { v0[i] = hb[i]; v1[i] = hb[i + 8]; }
  *(us8*)(xn + (size_t)(n0 + r) * DD + d0 + cseg) = v0;
  *(us8*)(xn + (size_t)(n0 + r) * DD + d0 + cseg + 8) = v1;
  __syncthreads();
  // transposed write: raw x
  const int drow = tid >> 2, nseg = (tid & 3) * 16;
  unsigned short hb2[16];
#pragma unroll
  for (int i = 0; i < 16; ++i)
    hb2[i] = __builtin_bit_cast(unsigned short, __float2bfloat16(tile[nseg + i][drow]));
  us8 w0, w1;
#pragma unroll
  for (int i = 0; i < 8; ++i) { w0[i] = hb2[i]; w1[i] = hb2[i + 8]; }
  *(us8*)(xT + (size_t)(d0 + drow) * N + n0 + nseg) = w0;
  *(us8*)(xT + (size_t)(d0 + drow) * N + n0 + nseg + 8) = w1;
}

// ---------------------------------------------------------------------------
// Kernel 3: Gram MFMA. C[a,b] = F(a,b) * (xn_a . xn_b), bf16 out + col_sum.
// 128x128 tile, BK=64, 4 waves (2x2), 4x4 fragments/wave, 16x16x32 bf16 MFMA.
// global_load_lds(16B) staging, T2 XOR swizzle (pre-swizzled source).
// ---------------------------------------------------------------------------
#define GBM 128
#define GBN 128
#define GBK 64

__global__ __launch_bounds__(256) void kern_gram(
    const __hip_bfloat16* __restrict__ xn, const int* __restrict__ codes,
    __hip_bfloat16* __restrict__ Cb, float* __restrict__ col_sum, int N)
{
  __shared__ __hip_bfloat16 As[GBM * GBK];
  __shared__ __hip_bfloat16 Bs[GBN * GBK];
  const int tid = threadIdx.x;
  const int a0 = blockIdx.y * GBM, b0 = blockIdx.x * GBN;
  const int lane = tid & 63, wid = tid >> 6;
  const int wr = wid >> 1, wc = wid & 1;

  const f32x4 fz = {0.f, 0.f, 0.f, 0.f};
  f32x4 acc[4][4];
#pragma unroll
  for (int m = 0; m < 4; ++m)
#pragma unroll
    for (int n = 0; n < 4; ++n) acc[m][n] = fz;

  int ldsoff[4]; size_t srcA[4], srcB[4];
#pragma unroll
  for (int i = 0; i < 4; ++i) {
    int p = i * 4096 + tid * 16;
    int row = p >> 7, c = (p >> 4) & 7;
    ldsoff[i] = p;
    size_t cc = (size_t)((c ^ (row & 7)) << 4);
    srcA[i] = (size_t)(a0 + row) * (DD * 2) + cc;
    srcB[i] = (size_t)(b0 + row) * (DD * 2) + cc;
  }
  const char* xc = (const char*)xn;

  for (int kc = 0; kc < DD * 2; kc += GBK * 2) {  // byte step over K
#pragma unroll
    for (int i = 0; i < 4; ++i) {
      gload16(xc + srcA[i] + kc, (char*)As + ldsoff[i]);
      gload16(xc + srcB[i] + kc, (char*)Bs + ldsoff[i]);
    }
    __syncthreads();
#pragma unroll
    for (int kk = 0; kk < 2; ++kk) {
      const int kb = kk * 64 + (lane >> 4) * 16;
      bf16x8 af[4], bfr[4];
#pragma unroll
      for (int m = 0; m < 4; ++m) {
        int r = wr * 64 + m * 16 + (lane & 15);
        af[m] = *(const bf16x8*)((const char*)As + r * 128 + (kb ^ ((r & 7) << 4)));
      }
#pragma unroll
      for (int n = 0; n < 4; ++n) {
        int r = wc * 64 + n * 16 + (lane & 15);
        bfr[n] = *(const bf16x8*)((const char*)Bs + r * 128 + (kb ^ ((r & 7) << 4)));
      }
#pragma unroll
      for (int m = 0; m < 4; ++m)
#pragma unroll
        for (int n = 0; n < 4; ++n)
          acc[m][n] = __builtin_amdgcn_mfma_f32_16x16x32_bf16(af[m], bfr[n], acc[m][n], 0, 0, 0);
    }
    __syncthreads();
  }

  // epilogue: F factor via packed nibble codes, bf16 C write, col_sum
  int cb[4], colidx[4];
#pragma unroll
  for (int n = 0; n < 4; ++n) {
    int b = b0 + wc * 64 + n * 16 + (lane & 15);
    colidx[n] = b;
    cb[n] = codes[b];
  }
  float colacc[4] = {0.f, 0.f, 0.f, 0.f};
  const int rbase = a0 + wr * 64 + ((lane >> 4) << 2);
#pragma unroll
  for (int m = 0; m < 4; ++m) {
#pragma unroll
    for (int j = 0; j < 4; ++j) {
      int a = rbase + m * 16 + j;
      int ca = codes[a];
#pragma unroll
      for (int n = 0; n < 4; ++n) {
        int t = ca ^ cb[n];
        t |= t >> 1; t |= t >> 2;
        t &= 0x111111;
        float f = (float)(6 - __popc(t)) * (1.0f / 6.0f);
        float cv = acc[m][n][j] * f;
        Cb[(size_t)a * N + colidx[n]] = __float2bfloat16(cv);
        colacc[n] += cv;
      }
    }
  }
#pragma unroll
  for (int n = 0; n < 4; ++n) {
    float v = colacc[n];
    v += __shfl_xor(v, 16);
    v += __shfl_xor(v, 32);
    if (lane < 16) atomicAdd(&col_sum[colidx[n]], v);
  }
}

// ---------------------------------------------------------------------------
// Kernel 4: out_second[b,d] = (1/N) sum_a C[b,a] * xT[d,a]   (C symmetric)
// 64x64 tile, BK=64, 4 waves (2x2), 2x2 fragments/wave.
// ---------------------------------------------------------------------------
#define OBM 64
#define OBN 64
#define OBK 64

__global__ __launch_bounds__(256) void kern_out2(
    const __hip_bfloat16* __restrict__ Cb, const __hip_bfloat16* __restrict__ xT,
    float* __restrict__ out, int N)
{
  __shared__ __hip_bfloat16 As[OBM * OBK];
  __shared__ __hip_bfloat16 Bs[OBN * OBK];
  const int tid = threadIdx.x;
  const int b0 = blockIdx.x * OBM, d0 = blockIdx.y * OBN;
  const int lane = tid & 63, wid = tid >> 6;
  const int wr = wid >> 1, wc = wid & 1;
  const f32x4 fz = {0.f, 0.f, 0.f, 0.f};
  f32x4 acc[2][2];
#pragma unroll
  for (int m = 0; m < 2; ++m)
#pragma unroll
    for (int n = 0; n < 2; ++n) acc[m][n] = fz;

  int ldsoff[2]; size_t srcA[2], srcB[2];
#pragma unroll
  for (int i = 0; i < 2; ++i) {
    int p = i * 4096 + tid * 16;
    int row = p >> 7, c = (p >> 4) & 7;
    ldsoff[i] = p;
    size_t cc = (size_t)((c ^ (row & 7)) << 4);
    srcA[i] = (size_t)(b0 + row) * ((size_t)N * 2) + cc;
    srcB[i] = (size_t)(d0 + row) * ((size_t)N * 2) + cc;
  }
  const char* Ac = (const char*)Cb;
  const char* Bc = (const char*)xT;

  for (size_t kc = 0; kc < (size_t)N * 2; kc += OBK * 2) {
#pragma unroll
    for (int i = 0; i < 2; ++i) {
      gload16(Ac + srcA[i] + kc, (char*)As + ldsoff[i]);
      gload16(Bc + srcB[i] + kc, (char*)Bs + ldsoff[i]);
    }
    __syncthreads();
#pragma unroll
    for (int kk = 0; kk < 2; ++kk) {
      const int kb = kk * 64 + (lane >> 4) * 16;
      bf16x8 af[2], bfr[2];
#pragma unroll
      for (int m = 0; m < 2; ++m) {
        int r = wr * 32 + m * 16 + (lane & 15);
        af[m] = *(const bf16x8*)((const char*)As + r * 128 + (kb ^ ((r & 7) << 4)));
      }
#pragma unroll
      for (int n = 0; n < 2; ++n) {
        int r = wc * 32 + n * 16 + (lane & 15);
        bfr[n] = *(const bf16x8*)((const char*)Bs + r * 128 + (kb ^ ((r & 7) << 4)));
      }
#pragma unroll
      for (int m = 0; m < 2; ++m)
#pragma unroll
        for (int n = 0; n < 2; ++n)
          acc[m][n] = __builtin_amdgcn_mfma_f32_16x16x32_bf16(af[m], bfr[n], acc[m][n], 0, 0, 0);
    }
    __syncthreads();
  }

  const float invN = 1.0f / (float)N;
#pragma unroll
  for (int m = 0; m < 2; ++m) {
#pragma unroll
    for (int j = 0; j < 4; ++j) {
      int r = wr * 32 + m * 16 + ((lane >> 4) << 2) + j;
#pragma unroll
      for (int n = 0; n < 2; ++n) {
        int c = wc * 32 + n * 16 + (lane & 15);
        out[(size_t)(b0 + r) * (2 * DD) + DD + d0 + c] = acc[m][n][j] * invN;
      }
    }
  }
}

// ---------------------------------------------------------------------------
// Kernel 5: out_first[n,d] = x[n,d] * col_sum[n] / N
// ---------------------------------------------------------------------------
__global__ __launch_bounds__(256) void kern_out1(
    const float* __restrict__ x, const float* __restrict__ col_sum,
    float* __restrict__ out, int N)
{
  int idx = blockIdx.x * 256 + threadIdx.x;
  int total = N * (DD / 4);
  if (idx >= total) return;
  int n = idx / (DD / 4);
  int d4 = idx - n * (DD / 4);
  float s = col_sum[n] * (1.0f / (float)N);
  float4 v = ((const float4*)(x + (size_t)n * DD))[d4];
  v.x *= s; v.y *= s; v.z *= s; v.w *= s;
  *(float4*)&out[(size_t)n * (2 * DD) + d4 * 4] = v;
}

extern "C" void kernel_launch(void* const* d_in, const int* in_sizes, int n_in,
                              void* d_out, int out_size, void* d_ws, size_t ws_size,
                              hipStream_t stream) {
  const float* x = (const float*)d_in[0];
  const float* H = (const float*)d_in[1];
  float* out = (float*)d_out;
  const int N = in_sizes[0] / DD;  // 4096

  char* ws = (char*)d_ws;
  __hip_bfloat16* Cb   = (__hip_bfloat16*)ws;                       // N*N bf16 (32 MB)
  __hip_bfloat16* xn16 = (__hip_bfloat16*)(ws + (size_t)N * N * 2); // N*DD bf16 (4 MB)
  __hip_bfloat16* xT16 = xn16 + (size_t)N * DD;                     // DD*N bf16 (4 MB)
  float* col_sum  = (float*)(xT16 + (size_t)N * DD);                // N f32
  float* inv_norm = col_sum + N;                                    // N f32
  int*   codes    = (int*)(inv_norm + N);                           // N int

  hipMemsetAsync(col_sum, 0, N * sizeof(float), stream);
  kern_wmax<<<N, 64, 0, stream>>>(x, H, codes, inv_norm);
  kern_prep<<<dim3(N / 64, DD / 64), 256, 0, stream>>>(x, inv_norm, xn16, xT16, N);
  kern_gram<<<dim3(N / GBN, N / GBM), 256, 0, stream>>>(xn16, codes, Cb, col_sum, N);
  kern_out2<<<dim3(N / OBM, DD / OBN), 256, 0, stream>>>(Cb, xT16, out, N);
  kern_out1<<<(N * (DD / 4) + 255) / 256, 256, 0, stream>>>(x, col_sum, out, N);
}